// Round 1
// baseline (166.461 us; speedup 1.0000x reference)
//
#include <hip/hip_runtime.h>
#include <math.h>

// Problem constants (match the reference)
constexpr int B    = 4;
constexpr int N    = 65536;   // 2^16
constexpr int NSUB = 16384;   // 2^14
constexpr int K    = 16;
constexpr int D    = 32;      // 8 float4 per row
constexpr int D4   = D / 4;   // 8

__device__ inline float4 fmax4(float4 a, float4 b) {
    return make_float4(fmaxf(a.x, b.x), fmaxf(a.y, b.y),
                       fmaxf(a.z, b.z), fmaxf(a.w, b.w));
}

// dst[b, r, :] = max_k src[b, idx[b, r, k], :]
// src has N rows per batch; idx/dst have M rows per batch.
// 8 threads per row, one float4 each (coalesced 128B per gathered row).
template<int M>
__global__ __launch_bounds__(256)
void gather_max_k(const float* __restrict__ src,
                  const int*   __restrict__ idx,
                  float*       __restrict__ dst)
{
    const int t = blockIdx.x * 256 + threadIdx.x;   // B*M*8 threads total
    const int r = t >> 3;                           // global row in [0, B*M)
    const int j = t & 7;                            // float4 slot within row
    const int b = r / M;                            // M is compile-time pow2 -> shift

    const int*    ip = idx + (size_t)r * K;
    const float4* sb = (const float4*)src + (size_t)b * N * D4;

    int n0 = ip[0];
    float4 m = sb[(size_t)n0 * D4 + j];
#pragma unroll
    for (int k = 1; k < K; ++k) {
        int nn = ip[k];
        float4 v = sb[(size_t)nn * D4 + j];
        m = fmax4(m, v);
    }
    ((float4*)dst)[(size_t)r * D4 + j] = m;
}

// out[b, n, :] += pooled[b, interp_idx[b, n], :]   (in-place on agg)
__global__ __launch_bounds__(256)
void interp_add_k(const float* __restrict__ pooled,
                  const int*   __restrict__ iidx,
                  float*       __restrict__ out)
{
    const int t = blockIdx.x * 256 + threadIdx.x;   // B*N*8 threads
    const int r = t >> 3;                           // global row in [0, B*N)
    const int j = t & 7;
    const int b = r >> 16;                          // r / N

    const int s = iidx[r];
    float4 p = ((const float4*)pooled)[((size_t)b * NSUB + s) * D4 + j];

    float4* op = (float4*)out + (size_t)r * D4 + j;
    float4 o = *op;
    *op = make_float4(o.x + p.x, o.y + p.y, o.z + p.z, o.w + p.w);
}

extern "C" void kernel_launch(void* const* d_in, const int* in_sizes, int n_in,
                              void* d_out, int out_size, void* d_ws, size_t ws_size,
                              hipStream_t stream)
{
    const float* feature      = (const float*)d_in[0]; // [B, N, 1, D]
    const int*   neighbor_idx = (const int*)  d_in[1]; // [B, N, K]
    const int*   pool_idx     = (const int*)  d_in[2]; // [B, NSUB, K]
    const int*   interp_idx   = (const int*)  d_in[3]; // [B, N, 1]

    float* out    = (float*)d_out;   // agg lives here, then out = agg + up in-place
    float* pooled = (float*)d_ws;    // B*NSUB*D floats = 8 MiB scratch

    // 1) agg[b,n,:] = max_k feature[b, nidx, :]  -> d_out
    {
        const int threads = B * N * 8;
        gather_max_k<N><<<threads / 256, 256, 0, stream>>>(feature, neighbor_idx, out);
    }
    // 2) pooled[b,m,:] = max_k agg[b, pidx, :]   -> d_ws
    {
        const int threads = B * NSUB * 8;
        gather_max_k<NSUB><<<threads / 256, 256, 0, stream>>>(out, pool_idx, pooled);
    }
    // 3) out[b,n,:] = agg[b,n,:] + pooled[b, interp_idx[b,n], :]
    {
        const int threads = B * N * 8;
        interp_add_k<<<threads / 256, 256, 0, stream>>>(pooled, interp_idx, out);
    }
}